// Round 13
// baseline (236.004 us; speedup 1.0000x reference)
//
#include <hip/hip_runtime.h>
#include <math.h>

#define Bc 8
#define Tc 60
#define Sc 36
#define Hc_ 4
#define Ec 16
#define PEc 16
#define ADc 12
#define TAc 10
#define OUTc 64
#define KEEP 648
#define EPSc 1e-5f
#define LOG1E4_8 1.15129254649702284f   // ln(10000)/8

// workspace layout (float offsets)
#define WS_H2     18176                    // B*H*T*S*E = 1105920  (layer-1 output)
#define WS_H1     1124096                  // 1105920              (layer-0 output)
#define WS_ALPHA  2230016                  // B*H*T*S*S = 2488320
#define WS_ADJ    4759808                  // B*H*S*S = 41472
#define WS_ADJP   4801280                  // B*H*6*S*S = 248832 (t-chunk partial sums)
#define WS_CNT    5050112                  // B*S = 288 (mask counts)
#define WS_BID1   5050400                  // B*H*S*S = 41472 (layer-1 bidir matrices)
#define WS_PET    5091872                  // B*T*PE = 7680 (PE table)
#define WS_TKT    5099552                  // 32 ints (kF2 completion tickets)
// final-chain buffers overlay the (dead-by-then) ALPHA region:
#define WS_BETA   WS_ALPHA                 // B*H*S*T = 69120
#define WS_PART   (WS_ALPHA + 69120)       // B*H*S*2 = 2304
#define WS_OUT2   (WS_ALPHA + 71424)       // B*H*S*16 = 18432
#define WS_PART2  (WS_ALPHA + 89856)       // B*H*S*2 = 2304

__device__ __forceinline__ float lrelu(float v){ return v >= 0.f ? v : 0.01f*v; }

// ---- kernel 1: BN(stats+apply) + embed + layer0 (alpha0,w0,mp -> h1) + alpha1 ----
__global__ __launch_bounds__(256) void k_layer01(const float* __restrict__ x,
                          const float* __restrict__ times,
                          const float* __restrict__ mask,
                          const float* __restrict__ bn_g,
                          const float* __restrict__ bn_b,
                          const float* __restrict__ obs_w,
                          const float* __restrict__ attn,
                          const float* __restrict__ bidw,
                          const float* __restrict__ projW,
                          const float* __restrict__ projb,
                          float* __restrict__ ws){
    int idx = blockIdx.x;                 // (b*H + h)*T + t
    int t = idx % Tc; int bh = idx / Tc; int h = bh % Hc_; int b = bh / Hc_;
    int tid = threadIdx.x;
    __shared__ float sh_h[Sc*Ec];
    __shared__ float sh_h1[Sc*Ec];
    __shared__ float sh_pe[PEc];
    __shared__ float sh_at0T[ADc*Sc];     // [d][j]
    __shared__ float sh_at1T[ADc*Sc];
    __shared__ float sh_bwT[ADc*Sc];
    __shared__ float sh_hp[Sc*28];
    __shared__ float sh_P[Sc];
    __shared__ float sh_w[Sc*Sc];
    __shared__ float sh_xn[Sc];
    __shared__ float sh_m[Sc];
    __shared__ float sred[8];
    float s0 = 0.f, s1 = 0.f;
    for (int i = tid; i < Bc*Sc; i += 256){
        float v = x[((i/Sc)*Tc + t)*Sc + (i%Sc)];
        s0 += v; s1 += v*v;
    }
    #pragma unroll
    for (int off = 32; off; off >>= 1){
        s0 += __shfl_down(s0, off, 64);
        s1 += __shfl_down(s1, off, 64);
    }
    if ((tid & 63) == 0){ sred[(tid>>6)*2] = s0; sred[(tid>>6)*2 + 1] = s1; }
    if (tid >= 64 && tid < 80){
        int q = tid - 64; int j = q >> 1;
        float ang = times[b*Tc + t] * expf(-(float)j * LOG1E4_8);
        sh_pe[q] = (q & 1) ? cosf(ang) : sinf(ang);
    }
    for (int i = tid; i < ADc*Sc; i += 256){
        int d = i / Sc, j = i % Sc;
        sh_at0T[i] = attn[h*Sc*ADc + j*ADc + d];
        sh_at1T[i] = attn[(Hc_ + h)*Sc*ADc + j*ADc + d];
        sh_bwT[i]  = bidw[h*Sc*ADc + j*ADc + d];
    }
    __syncthreads();
    float mu  = (sred[0]+sred[2]+sred[4]+sred[6]) / (float)(Bc*Sc);
    float var = (sred[1]+sred[3]+sred[5]+sred[7]) / (float)(Bc*Sc) - mu*mu;
    if (tid < Sc){
        float xv = x[(b*Tc + t)*Sc + tid];
        sh_xn[tid] = (xv - mu) * rsqrtf(var + EPSc) * bn_g[t] + bn_b[t];
        sh_m[tid]  = mask[(b*Tc + t)*Sc + tid];
    }
    __syncthreads();
    for (int i = tid; i < Sc*Ec; i += 256){
        int s = i / Ec, e = i % Ec;
        sh_h[i] = lrelu(sh_xn[s]*obs_w[s*64 + h*Ec + e]) * sh_m[s];
    }
    __syncthreads();
    for (int i = tid; i < Sc*28; i += 256){
        int s = i / 28, d = i % 28;
        float acc = projb[d];
        const float* w = projW + d*Ec;
        const float* hh = sh_h + s*Ec;
        #pragma unroll
        for (int e = 0; e < Ec; e++) acc += hh[e]*w[e];
        sh_hp[i] = acc;
    }
    __syncthreads();
    if (tid < Sc){
        const float* hp = sh_hp + tid*28 + ADc;
        float p = 0.f;
        #pragma unroll
        for (int d = 0; d < PEc; d++) p += hp[d]*sh_pe[d];
        sh_P[tid] = p;
    }
    __syncthreads();
    for (int i = tid; i < Sc*Sc; i += 256){
        int s = i / Sc, j = i % Sc;
        const float* hp = sh_hp + s*28;
        float acc = sh_P[s];
        float bd = 0.f;
        #pragma unroll
        for (int d = 0; d < ADc; d++){
            acc += hp[d]*sh_at0T[d*Sc + j];
            bd  += sh_bwT[d*Sc + s]*sh_bwT[d*Sc + j];
        }
        sh_w[i] = lrelu(lrelu(bd)*lrelu(acc));
    }
    __syncthreads();
    float* h1g = ws + WS_H1 + (size_t)idx*Sc*Ec;
    for (int i = tid; i < Sc*Ec; i += 256){
        int s = i / Ec, e = i % Ec;
        float acc = 0.f;
        #pragma unroll 6
        for (int j = 0; j < Sc; j++) acc += lrelu(sh_h[j*Ec + e]*sh_w[s*Sc + j]);
        float v = lrelu(acc);
        sh_h1[i] = v;
        h1g[i] = v;
    }
    __syncthreads();
    for (int i = tid; i < Sc*28; i += 256){
        int s = i / 28, d = i % 28;
        float acc = projb[d];
        const float* w = projW + d*Ec;
        const float* hh = sh_h1 + s*Ec;
        #pragma unroll
        for (int e = 0; e < Ec; e++) acc += hh[e]*w[e];
        sh_hp[i] = acc;
    }
    __syncthreads();
    if (tid < Sc){
        const float* hp = sh_hp + tid*28 + ADc;
        float p = 0.f;
        #pragma unroll
        for (int d = 0; d < PEc; d++) p += hp[d]*sh_pe[d];
        sh_P[tid] = p;
    }
    __syncthreads();
    float* adst = ws + WS_ALPHA + (size_t)idx*Sc*Sc;
    for (int i = tid; i < Sc*Sc; i += 256){
        int s = i / Sc, j = i % Sc;
        const float* hp = sh_hp + s*28;
        float acc = sh_P[s];
        #pragma unroll
        for (int d = 0; d < ADc; d++) acc += hp[d]*sh_at1T[d*Sc + j];
        adst[i] = lrelu(acc);
    }
}

// ---- kernel 2a: partial t-sum of alpha + hoisted precomputes (mask counts,
//      layer-1 bidir matrices, PE table, ticket zeroing) ----
__global__ __launch_bounds__(256) void k_adjpart(const float* __restrict__ mask,
                          const float* __restrict__ bidw,
                          const float* __restrict__ times,
                          float* __restrict__ ws){
    int bh = blockIdx.x / 6; int chunk = blockIdx.x % 6;
    int tid = threadIdx.x;
    const float4* a = (const float4*)(ws + WS_ALPHA + (size_t)bh*Tc*Sc*Sc) + (size_t)chunk*10*324;
    float4* p = (float4*)(ws + WS_ADJP + (size_t)blockIdx.x*Sc*Sc);
    for (int c = tid; c < 324; c += 256){
        float4 acc = make_float4(0.f, 0.f, 0.f, 0.f);
        #pragma unroll
        for (int tt = 0; tt < 10; tt++){
            float4 u = a[(size_t)tt*324 + c];
            acc.x += u.x; acc.y += u.y; acc.z += u.z; acc.w += u.w;
        }
        p[c] = acc;
    }
    if (chunk == 0 && (bh & 3) == 0 && tid < Sc){   // mask counts per batch
        int b = bh >> 2;
        float c = 0.f;
        #pragma unroll 4
        for (int t = 0; t < Tc; t++) c += mask[(b*Tc + t)*Sc + tid];
        ws[WS_CNT + b*Sc + tid] = c;
    }
    if (blockIdx.x == 0 && tid < 32)                // zero kF2 tickets
        ((int*)(ws + WS_TKT))[tid] = 0;
    if (chunk == 1){                                // BID1[bh][s][j]
        int h = bh % Hc_;
        const float* bw = bidw + (Hc_ + h)*Sc*ADc;
        for (int i = tid; i < Sc*Sc; i += 256){
            int s = i / Sc, j = i % Sc;
            float bd = 0.f;
            #pragma unroll
            for (int d = 0; d < ADc; d++) bd += bw[s*ADc + d]*bw[j*ADc + d];
            ws[WS_BID1 + bh*Sc*Sc + i] = lrelu(bd);
        }
    }
    if (chunk == 2 && (bh & 3) == 0){               // PE table per batch
        int b = bh >> 2;
        for (int i = tid; i < Tc*PEc; i += 256){
            int t = i / PEc, q = i % PEc; int j = q >> 1;
            float ang = times[b*Tc + t] * expf(-(float)j * LOG1E4_8);
            ws[WS_PET + (b*Tc + t)*PEc + q] = (q & 1) ? cosf(ang) : sinf(ang);
        }
    }
}

// ---- kernel 2b: stable-rank prune, 4-way split scan (768 blocks, proven R12) ----
__global__ __launch_bounds__(256) void k_prune(float* __restrict__ ws){
    int bh = blockIdx.x / 24; int chunk = blockIdx.x % 24;
    int b = bh >> 2;
    int tid = threadIdx.x;
    __shared__ __align__(16) float sh_v[Sc*Sc];
    __shared__ float sh_cnt[Sc];
    const float4* p = (const float4*)(ws + WS_ADJP + (size_t)bh*6*Sc*Sc);
    for (int c = tid; c < 324; c += 256){
        float4 acc = make_float4(0.f, 0.f, 0.f, 0.f);
        #pragma unroll
        for (int q = 0; q < 6; q++){
            float4 u = p[(size_t)q*324 + c];
            acc.x += u.x; acc.y += u.y; acc.z += u.z; acc.w += u.w;
        }
        ((float4*)sh_v)[c] = acc;
    }
    if (tid < Sc) sh_cnt[tid] = ws[WS_CNT + b*Sc + tid];
    __syncthreads();
    for (int i = tid; i < Sc*Sc; i += 256){
        int s = i / Sc;
        sh_v[i] = lrelu(sh_v[i] / sh_cnt[s]);
    }
    __syncthreads();
    int r = tid >> 2; if (r > 53) r = 53;
    int part = tid & 3;
    int i = chunk*54 + r;
    float v = sh_v[i];
    const float4* v4 = (const float4*)sh_v + part*81;
    int a0 = part*324;
    int cnt = 0;
    #pragma unroll 9
    for (int j = 0; j < 81; j++){
        float4 u = v4[j];
        int k = a0 + j*4;
        cnt += (int)(u.x < v) + ((int)(u.x == v) & (int)(k   < i));
        cnt += (int)(u.y < v) + ((int)(u.y == v) & (int)(k+1 < i));
        cnt += (int)(u.z < v) + ((int)(u.z == v) & (int)(k+2 < i));
        cnt += (int)(u.w < v) + ((int)(u.w == v) & (int)(k+3 < i));
    }
    cnt += __shfl_down(cnt, 2, 4);
    cnt += __shfl_down(cnt, 1, 4);
    if (part == 0 && tid < 216)
        ws[WS_ADJ + bh*Sc*Sc + i] = (cnt >= KEEP) ? v : 0.f;
}

// ---- kernel 3: layer 1 message passing (BID1 precomputed); block 1920 = pair_sim ----
__global__ __launch_bounds__(256) void k_layer1mp(float* __restrict__ ws, float* __restrict__ out){
    int tid = threadIdx.x;
    if (blockIdx.x == Bc*Hc_*Tc){
        float sq = 0.f, t2 = 0.f;
        for (int i = tid; i < Hc_*Sc*Sc; i += 256){
            float tot = 0.f;
            #pragma unroll
            for (int b = 0; b < Bc; b++){
                float v = ws[WS_ADJ + b*Hc_*Sc*Sc + i];
                sq += v*v; tot += v;
            }
            t2 += tot*tot;
        }
        __shared__ float r0[256], r1[256];
        r0[tid] = sq; r1[tid] = t2; __syncthreads();
        for (int off = 128; off; off >>= 1){
            if (tid < off){ r0[tid] += r0[tid+off]; r1[tid] += r1[tid+off]; }
            __syncthreads();
        }
        if (tid == 0)
            out[Bc*Sc*OUTc] = ((float)Bc*r0[0] - r1[0]) / 49.f / 1296.f;
        return;
    }
    int idx = blockIdx.x;
    int bh = idx / Tc;
    __shared__ float sh_h[Sc*Ec];
    __shared__ float sh_w[Sc*Sc];
    const float* hsrc = ws + WS_H1 + (size_t)idx*Sc*Ec;
    float*       hdst = ws + WS_H2 + (size_t)idx*Sc*Ec;
    const float* al  = ws + WS_ALPHA + (size_t)idx*Sc*Sc;
    const float* adj = ws + WS_ADJ + bh*Sc*Sc;
    const float* bid = ws + WS_BID1 + bh*Sc*Sc;
    for (int i = tid; i < Sc*Ec; i += 256) sh_h[i] = hsrc[i];
    for (int i = tid; i < Sc*Sc; i += 256)
        sh_w[i] = lrelu(bid[i]*al[i]*adj[i]);
    __syncthreads();
    for (int i = tid; i < Sc*Ec; i += 256){
        int s = i / Ec, e = i % Ec;
        float acc = 0.f;
        #pragma unroll 6
        for (int j = 0; j < Sc; j++) acc += lrelu(sh_h[j*Ec + e]*sh_w[s*Sc + j]);
        hdst[i] = lrelu(acc);
    }
}

// ------- kernel 4: per-(bh,s) temporal attention: beta + LN1 partials -------
__global__ __launch_bounds__(64) void kF1(const float* __restrict__ Wq, const float* __restrict__ bq,
                   const float* __restrict__ Wk, const float* __restrict__ bk,
                   const float* __restrict__ Ws_, const float* __restrict__ bs_,
                   float* __restrict__ ws){
    int idx = blockIdx.x;                  // bh*Sc + s
    int s = idx % Sc; int bh = idx / Sc; int b = bh / Hc_;
    int tid = threadIdx.x;
    __shared__ float sh_Hc[Tc*33];         // row-pad 33
    __shared__ float sh_K[Tc*11];
    __shared__ float sh_Wq[TAc*32];
    __shared__ float sh_WkT[32*TAc];       // [q][d]
    __shared__ float sh_bq[TAc], sh_bk[TAc];
    __shared__ float sh_ws[Tc];
    __shared__ float sh_Kw[TAc];
    const float* h2 = ws + WS_H2 + (size_t)bh*Tc*Sc*Ec + s*Ec;
    for (int i4 = tid; i4 < Tc*4; i4 += 64){
        int t = i4 >> 2, c4 = i4 & 3;
        float4 u = *(const float4*)(h2 + t*Sc*Ec + c4*4);
        float* d = sh_Hc + t*33 + c4*4;
        d[0] = u.x; d[1] = u.y; d[2] = u.z; d[3] = u.w;
    }
    const float* pet = ws + WS_PET + b*Tc*PEc;
    for (int i = tid; i < Tc*PEc; i += 64)
        sh_Hc[(i/PEc)*33 + Ec + (i%PEc)] = pet[i];
    for (int i = tid; i < TAc*32; i += 64){
        sh_Wq[i] = Wq[i];
        int d = i / 32, q = i % 32;
        sh_WkT[q*TAc + d] = Wk[i];
    }
    if (tid < TAc){ sh_bq[tid] = bq[tid]; sh_bk[tid] = bk[tid]; }
    if (tid < Tc) sh_ws[tid] = Ws_[tid];
    __syncthreads();
    for (int i = tid; i < Tc*TAc; i += 64){
        int t = i / TAc, d = i % TAc;
        const float* hc = sh_Hc + t*33;
        float acc = sh_bk[d];
        #pragma unroll
        for (int q = 0; q < 32; q++) acc += hc[q]*sh_WkT[q*TAc + d];
        sh_K[t*11 + d] = acc;
    }
    __syncthreads();
    if (tid < TAc){
        float acc = 0.f;
        #pragma unroll 4
        for (int t = 0; t < Tc; t++) acc += sh_K[t*11 + tid]*sh_ws[t];
        sh_Kw[tid] = acc;
    }
    __syncthreads();
    float bv = 0.f;
    float bsv = bs_[0];
    if (tid < Tc){
        const float* hc = sh_Hc + tid*33;
        float acc = bsv;
        #pragma unroll
        for (int d = 0; d < TAc; d++){
            const float* wq = sh_Wq + d*32;
            float qv = sh_bq[d];
            #pragma unroll
            for (int q = 0; q < 32; q++) qv += hc[q]*wq[q];
            acc += qv*sh_Kw[d];
        }
        bv = acc;
        ws[WS_BETA + idx*Tc + tid] = acc;
    }
    float p0 = (tid < Tc) ? bv : 0.f;
    float p1 = p0*bv;
    #pragma unroll
    for (int off = 32; off; off >>= 1){
        p0 += __shfl_down(p0, off, 64);
        p1 += __shfl_down(p1, off, 64);
    }
    if (tid == 0){
        ws[WS_PART + idx*2]     = p0;
        ws[WS_PART + idx*2 + 1] = p1;
    }
}

// ------- kernel 5: per-(bh,s) LN1-normalize + out1 + out2 + LN2 partials;
//         last block per bh (ticket) performs LN2 + final output write -------
__global__ __launch_bounds__(64) void kF2(const float* __restrict__ lnt_g, const float* __restrict__ lnt_b,
                   const float* __restrict__ Wse, const float* __restrict__ bse,
                   const float* __restrict__ lns_g, const float* __restrict__ lns_b,
                   float* __restrict__ ws, float* __restrict__ out){
    int idx = blockIdx.x;
    int s = idx % Sc; int bh = idx / Sc; int b = bh / Hc_; int h = bh % Hc_;
    int tid = threadIdx.x;
    __shared__ float sh_Hc[Tc*33];
    __shared__ float sh_beta[Tc];
    __shared__ float sh_o1[32];
    __shared__ float sh_mi[2];
    __shared__ int sh_last;
    float p0 = 0.f, p1 = 0.f;
    if (tid < Sc){
        p0 = ws[WS_PART + (bh*Sc + tid)*2];
        p1 = ws[WS_PART + (bh*Sc + tid)*2 + 1];
    }
    #pragma unroll
    for (int off = 32; off; off >>= 1){
        p0 += __shfl_down(p0, off, 64);
        p1 += __shfl_down(p1, off, 64);
    }
    if (tid == 0){
        float m = p0 / (float)(Sc*Tc);
        sh_mi[0] = m;
        sh_mi[1] = rsqrtf(p1 / (float)(Sc*Tc) - m*m + EPSc);
    }
    const float* h2 = ws + WS_H2 + (size_t)bh*Tc*Sc*Ec + s*Ec;
    for (int i4 = tid; i4 < Tc*4; i4 += 64){
        int t = i4 >> 2, c4 = i4 & 3;
        float4 u = *(const float4*)(h2 + t*Sc*Ec + c4*4);
        float* d = sh_Hc + t*33 + c4*4;
        d[0] = u.x; d[1] = u.y; d[2] = u.z; d[3] = u.w;
    }
    const float* pet = ws + WS_PET + b*Tc*PEc;
    for (int i = tid; i < Tc*PEc; i += 64)
        sh_Hc[(i/PEc)*33 + Ec + (i%PEc)] = pet[i];
    __syncthreads();
    float m = sh_mi[0], inv = sh_mi[1];
    if (tid < Tc){
        float bvv = ws[WS_BETA + idx*Tc + tid];
        sh_beta[tid] = (bvv - m)*inv*lnt_g[s*Tc + tid] + lnt_b[s*Tc + tid];
    }
    __syncthreads();
    if (tid < 32){
        float acc = 0.f;
        #pragma unroll 4
        for (int t = 0; t < Tc; t++) acc += sh_beta[t]*sh_Hc[t*33 + tid];
        sh_o1[tid] = lrelu(acc);
    }
    __syncthreads();
    float v = 0.f;
    if (tid < 16){
        float acc = bse[tid];
        const float* w = Wse + tid*32;
        #pragma unroll
        for (int d = 0; d < 32; d++) acc += sh_o1[d]*w[d];
        v = lrelu(acc);
        ws[WS_OUT2 + idx*16 + tid] = v;
    }
    float q0 = v, q1 = v*v;
    #pragma unroll
    for (int off = 32; off; off >>= 1){
        q0 += __shfl_down(q0, off, 64);
        q1 += __shfl_down(q1, off, 64);
    }
    if (tid == 0){
        ws[WS_PART2 + idx*2]     = q0;
        ws[WS_PART2 + idx*2 + 1] = q1;
    }
    // completion ticket: last block of this bh does LN2 + final write
    __threadfence();
    if (tid == 0){
        int old = atomicAdd((int*)(ws + WS_TKT) + bh, 1);
        sh_last = (old == Sc - 1);
    }
    __syncthreads();
    if (!sh_last) return;
    __threadfence();   // acquire: other blocks' OUT2/PART2 now visible
    float r0 = 0.f, r1 = 0.f;
    if (tid < Sc){
        r0 = ws[WS_PART2 + (bh*Sc + tid)*2];
        r1 = ws[WS_PART2 + (bh*Sc + tid)*2 + 1];
    }
    #pragma unroll
    for (int off = 32; off; off >>= 1){
        r0 += __shfl_down(r0, off, 64);
        r1 += __shfl_down(r1, off, 64);
    }
    if (tid == 0){
        float m2 = r0 / (float)(Sc*16);
        sh_mi[0] = m2;
        sh_mi[1] = rsqrtf(r1 / (float)(Sc*16) - m2*m2 + EPSc);
    }
    __syncthreads();
    float m2 = sh_mi[0], inv2 = sh_mi[1];
    for (int i = tid; i < Sc*16; i += 64){
        int ss = i / 16, k = i % 16;
        float vv = ws[WS_OUT2 + bh*Sc*16 + i];
        out[(b*Sc + ss)*OUTc + h*16 + k] = (vv - m2)*inv2*lns_g[i] + lns_b[i];
    }
}

extern "C" void kernel_launch(void* const* d_in, const int* in_sizes, int n_in,
                              void* d_out, int out_size, void* d_ws, size_t ws_size,
                              hipStream_t stream){
    const float* x     = (const float*)d_in[0];
    const float* times = (const float*)d_in[1];
    const float* mask  = (const float*)d_in[2];
    const float* bn_g  = (const float*)d_in[3];
    const float* bn_b  = (const float*)d_in[4];
    const float* obs   = (const float*)d_in[5];
    const float* attn  = (const float*)d_in[6];
    const float* bidw  = (const float*)d_in[7];
    const float* projW = (const float*)d_in[8];
    const float* projb = (const float*)d_in[9];
    const float* Wq    = (const float*)d_in[10];
    const float* bq    = (const float*)d_in[11];
    const float* Wk    = (const float*)d_in[12];
    const float* bk    = (const float*)d_in[13];
    const float* Ws_   = (const float*)d_in[14];
    const float* bs_   = (const float*)d_in[15];
    const float* lnt_g = (const float*)d_in[16];
    const float* lnt_b = (const float*)d_in[17];
    const float* Wse   = (const float*)d_in[18];
    const float* bse   = (const float*)d_in[19];
    const float* lns_g = (const float*)d_in[20];
    const float* lns_b = (const float*)d_in[21];
    float* ws  = (float*)d_ws;
    float* out = (float*)d_out;

    k_layer01<<<Bc*Hc_*Tc, 256, 0, stream>>>(x, times, mask, bn_g, bn_b, obs, attn, bidw, projW, projb, ws);
    k_adjpart<<<Bc*Hc_*6, 256, 0, stream>>>(mask, bidw, times, ws);
    k_prune<<<Bc*Hc_*24, 256, 0, stream>>>(ws);
    k_layer1mp<<<Bc*Hc_*Tc + 1, 256, 0, stream>>>(ws, out);
    kF1<<<Bc*Hc_*Sc, 64, 0, stream>>>(Wq, bq, Wk, bk, Ws_, bs_, ws);
    kF2<<<Bc*Hc_*Sc, 64, 0, stream>>>(lnt_g, lnt_b, Wse, bse, lns_g, lns_b, ws, out);
}

// Round 14
// 208.990 us; speedup vs baseline: 1.1293x; 1.1293x over previous
//
#include <hip/hip_runtime.h>
#include <math.h>

#define Bc 8
#define Tc 60
#define Sc 36
#define Hc_ 4
#define Ec 16
#define PEc 16
#define ADc 12
#define TAc 10
#define OUTc 64
#define KEEP 648
#define EPSc 1e-5f
#define LOG1E4_8 1.15129254649702284f   // ln(10000)/8

// workspace layout (float offsets)
#define WS_H2     18176                    // B*H*T*S*E = 1105920  (layer-1 output)
#define WS_H1     1124096                  // 1105920              (layer-0 output)
#define WS_ALPHA  2230016                  // B*H*T*S*S = 2488320
#define WS_ADJ    4759808                  // B*H*S*S = 41472
#define WS_ADJP   4801280                  // B*H*6*S*S = 248832 (t-chunk partial sums)
#define WS_CNT    5050112                  // B*S = 288 (mask counts)
// final-chain buffers overlay the (dead-by-then) ALPHA region:
#define WS_BETA   WS_ALPHA                 // B*H*S*T = 69120
#define WS_PART   (WS_ALPHA + 69120)       // B*H*S*2 = 2304
#define WS_OUT2   (WS_ALPHA + 71424)       // B*H*S*16 = 18432
#define WS_PART2  (WS_ALPHA + 89856)       // B*H*S*2 = 2304

__device__ __forceinline__ float lrelu(float v){ return v >= 0.f ? v : 0.01f*v; }

// ---- kernel 1: BN(stats+apply) + embed + layer0 (alpha0,w0,mp -> h1) + alpha1 ----
__global__ __launch_bounds__(256) void k_layer01(const float* __restrict__ x,
                          const float* __restrict__ times,
                          const float* __restrict__ mask,
                          const float* __restrict__ bn_g,
                          const float* __restrict__ bn_b,
                          const float* __restrict__ obs_w,
                          const float* __restrict__ attn,
                          const float* __restrict__ bidw,
                          const float* __restrict__ projW,
                          const float* __restrict__ projb,
                          float* __restrict__ ws){
    int idx = blockIdx.x;                 // (b*H + h)*T + t
    int t = idx % Tc; int bh = idx / Tc; int h = bh % Hc_; int b = bh / Hc_;
    int tid = threadIdx.x;
    __shared__ float sh_h[Sc*Ec];
    __shared__ float sh_h1[Sc*Ec];
    __shared__ float sh_pe[PEc];
    __shared__ float sh_at0T[ADc*Sc];     // [d][j]
    __shared__ float sh_at1T[ADc*Sc];
    __shared__ float sh_bwT[ADc*Sc];
    __shared__ float sh_hp[Sc*28];
    __shared__ float sh_P[Sc];
    __shared__ float sh_w[Sc*Sc];
    __shared__ float sh_xn[Sc];
    __shared__ float sh_m[Sc];
    __shared__ float sred[8];
    float s0 = 0.f, s1 = 0.f;
    for (int i = tid; i < Bc*Sc; i += 256){
        float v = x[((i/Sc)*Tc + t)*Sc + (i%Sc)];
        s0 += v; s1 += v*v;
    }
    #pragma unroll
    for (int off = 32; off; off >>= 1){
        s0 += __shfl_down(s0, off, 64);
        s1 += __shfl_down(s1, off, 64);
    }
    if ((tid & 63) == 0){ sred[(tid>>6)*2] = s0; sred[(tid>>6)*2 + 1] = s1; }
    if (tid >= 64 && tid < 80){
        int q = tid - 64; int j = q >> 1;
        float ang = times[b*Tc + t] * expf(-(float)j * LOG1E4_8);
        sh_pe[q] = (q & 1) ? cosf(ang) : sinf(ang);
    }
    for (int i = tid; i < ADc*Sc; i += 256){
        int d = i / Sc, j = i % Sc;
        sh_at0T[i] = attn[h*Sc*ADc + j*ADc + d];
        sh_at1T[i] = attn[(Hc_ + h)*Sc*ADc + j*ADc + d];
        sh_bwT[i]  = bidw[h*Sc*ADc + j*ADc + d];
    }
    __syncthreads();
    float mu  = (sred[0]+sred[2]+sred[4]+sred[6]) / (float)(Bc*Sc);
    float var = (sred[1]+sred[3]+sred[5]+sred[7]) / (float)(Bc*Sc) - mu*mu;
    if (tid < Sc){
        float xv = x[(b*Tc + t)*Sc + tid];
        sh_xn[tid] = (xv - mu) * rsqrtf(var + EPSc) * bn_g[t] + bn_b[t];
        sh_m[tid]  = mask[(b*Tc + t)*Sc + tid];
    }
    __syncthreads();
    for (int i = tid; i < Sc*Ec; i += 256){
        int s = i / Ec, e = i % Ec;
        sh_h[i] = lrelu(sh_xn[s]*obs_w[s*64 + h*Ec + e]) * sh_m[s];
    }
    __syncthreads();
    for (int i = tid; i < Sc*28; i += 256){
        int s = i / 28, d = i % 28;
        float acc = projb[d];
        const float* w = projW + d*Ec;
        const float* hh = sh_h + s*Ec;
        #pragma unroll
        for (int e = 0; e < Ec; e++) acc += hh[e]*w[e];
        sh_hp[i] = acc;
    }
    __syncthreads();
    if (tid < Sc){
        const float* hp = sh_hp + tid*28 + ADc;
        float p = 0.f;
        #pragma unroll
        for (int d = 0; d < PEc; d++) p += hp[d]*sh_pe[d];
        sh_P[tid] = p;
    }
    __syncthreads();
    for (int i = tid; i < Sc*Sc; i += 256){
        int s = i / Sc, j = i % Sc;
        const float* hp = sh_hp + s*28;
        float acc = sh_P[s];
        float bd = 0.f;
        #pragma unroll
        for (int d = 0; d < ADc; d++){
            acc += hp[d]*sh_at0T[d*Sc + j];
            bd  += sh_bwT[d*Sc + s]*sh_bwT[d*Sc + j];
        }
        sh_w[i] = lrelu(lrelu(bd)*lrelu(acc));
    }
    __syncthreads();
    float* h1g = ws + WS_H1 + (size_t)idx*Sc*Ec;
    for (int i = tid; i < Sc*Ec; i += 256){
        int s = i / Ec, e = i % Ec;
        float acc = 0.f;
        #pragma unroll 6
        for (int j = 0; j < Sc; j++) acc += lrelu(sh_h[j*Ec + e]*sh_w[s*Sc + j]);
        float v = lrelu(acc);
        sh_h1[i] = v;
        h1g[i] = v;
    }
    __syncthreads();
    for (int i = tid; i < Sc*28; i += 256){
        int s = i / 28, d = i % 28;
        float acc = projb[d];
        const float* w = projW + d*Ec;
        const float* hh = sh_h1 + s*Ec;
        #pragma unroll
        for (int e = 0; e < Ec; e++) acc += hh[e]*w[e];
        sh_hp[i] = acc;
    }
    __syncthreads();
    if (tid < Sc){
        const float* hp = sh_hp + tid*28 + ADc;
        float p = 0.f;
        #pragma unroll
        for (int d = 0; d < PEc; d++) p += hp[d]*sh_pe[d];
        sh_P[tid] = p;
    }
    __syncthreads();
    float* adst = ws + WS_ALPHA + (size_t)idx*Sc*Sc;
    for (int i = tid; i < Sc*Sc; i += 256){
        int s = i / Sc, j = i % Sc;
        const float* hp = sh_hp + s*28;
        float acc = sh_P[s];
        #pragma unroll
        for (int d = 0; d < ADc; d++) acc += hp[d]*sh_at1T[d*Sc + j];
        adst[i] = lrelu(acc);
    }
}

// ---- kernel 2a: per-(bh, t-chunk) partial t-sum of alpha; also mask counts ----
__global__ __launch_bounds__(256) void k_adjpart(const float* __restrict__ mask, float* __restrict__ ws){
    int bh = blockIdx.x / 6; int chunk = blockIdx.x % 6;
    int tid = threadIdx.x;
    const float4* a = (const float4*)(ws + WS_ALPHA + (size_t)bh*Tc*Sc*Sc) + (size_t)chunk*10*324;
    float4* p = (float4*)(ws + WS_ADJP + (size_t)blockIdx.x*Sc*Sc);
    for (int c = tid; c < 324; c += 256){
        float4 acc = make_float4(0.f, 0.f, 0.f, 0.f);
        #pragma unroll
        for (int tt = 0; tt < 10; tt++){
            float4 u = a[(size_t)tt*324 + c];
            acc.x += u.x; acc.y += u.y; acc.z += u.z; acc.w += u.w;
        }
        p[c] = acc;
    }
    if (chunk == 0 && (bh & 3) == 0 && tid < Sc){
        int b = bh >> 2;
        float c = 0.f;
        #pragma unroll 4
        for (int t = 0; t < Tc; t++) c += mask[(b*Tc + t)*Sc + tid];
        ws[WS_CNT + b*Sc + tid] = c;
    }
}

// ---- kernel 2b: stable-rank prune, 4-way split scan (768 blocks; R12 proven) ----
__global__ __launch_bounds__(256) void k_prune(float* __restrict__ ws){
    int bh = blockIdx.x / 24; int chunk = blockIdx.x % 24;
    int b = bh >> 2;
    int tid = threadIdx.x;
    __shared__ __align__(16) float sh_v[Sc*Sc];
    __shared__ float sh_cnt[Sc];
    const float4* p = (const float4*)(ws + WS_ADJP + (size_t)bh*6*Sc*Sc);
    for (int c = tid; c < 324; c += 256){
        float4 acc = make_float4(0.f, 0.f, 0.f, 0.f);
        #pragma unroll
        for (int q = 0; q < 6; q++){
            float4 u = p[(size_t)q*324 + c];
            acc.x += u.x; acc.y += u.y; acc.z += u.z; acc.w += u.w;
        }
        ((float4*)sh_v)[c] = acc;
    }
    if (tid < Sc) sh_cnt[tid] = ws[WS_CNT + b*Sc + tid];
    __syncthreads();
    for (int i = tid; i < Sc*Sc; i += 256){
        int s = i / Sc;
        sh_v[i] = lrelu(sh_v[i] / sh_cnt[s]);
    }
    __syncthreads();
    int r = tid >> 2; if (r > 53) r = 53;
    int part = tid & 3;
    int i = chunk*54 + r;
    float v = sh_v[i];
    const float4* v4 = (const float4*)sh_v + part*81;
    int a0 = part*324;
    int cnt = 0;
    #pragma unroll 9
    for (int j = 0; j < 81; j++){
        float4 u = v4[j];
        int k = a0 + j*4;
        cnt += (int)(u.x < v) + ((int)(u.x == v) & (int)(k   < i));
        cnt += (int)(u.y < v) + ((int)(u.y == v) & (int)(k+1 < i));
        cnt += (int)(u.z < v) + ((int)(u.z == v) & (int)(k+2 < i));
        cnt += (int)(u.w < v) + ((int)(u.w == v) & (int)(k+3 < i));
    }
    cnt += __shfl_down(cnt, 2, 4);
    cnt += __shfl_down(cnt, 1, 4);
    if (part == 0 && tid < 216)
        ws[WS_ADJ + bh*Sc*Sc + i] = (cnt >= KEEP) ? v : 0.f;
}

// ---------------- kernel 3: layer 1 message passing ----------------
__global__ __launch_bounds__(256) void k_layer1mp(const float* __restrict__ bidw,
                                                  float* __restrict__ ws){
    int idx = blockIdx.x;
    int bh = idx / Tc; int h = bh % Hc_;
    int tid = threadIdx.x;
    __shared__ float sh_h[Sc*Ec];
    __shared__ float sh_w[Sc*Sc];
    __shared__ float sh_bwT[ADc*Sc];      // [d][s]
    const float* hsrc = ws + WS_H1 + (size_t)idx*Sc*Ec;
    float*       hdst = ws + WS_H2 + (size_t)idx*Sc*Ec;
    const float* al  = ws + WS_ALPHA + (size_t)idx*Sc*Sc;
    const float* adj = ws + WS_ADJ + bh*Sc*Sc;
    for (int i = tid; i < Sc*Ec; i += 256) sh_h[i] = hsrc[i];
    for (int i = tid; i < ADc*Sc; i += 256){
        int d = i / Sc, j = i % Sc;
        sh_bwT[i] = bidw[(Hc_ + h)*Sc*ADc + j*ADc + d];
    }
    __syncthreads();
    for (int i = tid; i < Sc*Sc; i += 256){
        int s = i / Sc, j = i % Sc;
        float bd = 0.f;
        #pragma unroll
        for (int d = 0; d < ADc; d++) bd += sh_bwT[d*Sc + s]*sh_bwT[d*Sc + j];
        sh_w[i] = lrelu(lrelu(bd)*al[i]*adj[i]);
    }
    __syncthreads();
    for (int i = tid; i < Sc*Ec; i += 256){
        int s = i / Ec, e = i % Ec;
        float acc = 0.f;
        #pragma unroll 6
        for (int j = 0; j < Sc; j++) acc += lrelu(sh_h[j*Ec + e]*sh_w[s*Sc + j]);
        hdst[i] = lrelu(acc);
    }
}

// ------- kernel 4: per-(bh,s) temporal attention: beta + LN1 partials -------
__global__ __launch_bounds__(64) void kF1(const float* __restrict__ Wq, const float* __restrict__ bq,
                   const float* __restrict__ Wk, const float* __restrict__ bk,
                   const float* __restrict__ Ws_, const float* __restrict__ bs_,
                   const float* __restrict__ times, float* __restrict__ ws){
    int idx = blockIdx.x;                  // bh*Sc + s
    int s = idx % Sc; int bh = idx / Sc; int b = bh / Hc_;
    int tid = threadIdx.x;
    __shared__ float sh_Hc[Tc*33];         // row-pad 33
    __shared__ float sh_K[Tc*11];
    __shared__ float sh_Wq[TAc*32];
    __shared__ float sh_WkT[32*TAc];       // [q][d]
    __shared__ float sh_bq[TAc], sh_bk[TAc];
    __shared__ float sh_ws[Tc];
    __shared__ float sh_Kw[TAc];
    const float* h2 = ws + WS_H2 + (size_t)bh*Tc*Sc*Ec + s*Ec;
    for (int i4 = tid; i4 < Tc*4; i4 += 64){
        int t = i4 >> 2, c4 = i4 & 3;
        float4 u = *(const float4*)(h2 + t*Sc*Ec + c4*4);
        float* d = sh_Hc + t*33 + c4*4;
        d[0] = u.x; d[1] = u.y; d[2] = u.z; d[3] = u.w;
    }
    for (int i = tid; i < Tc*PEc; i += 64){
        int t = i / PEc, q = i % PEc; int j = q >> 1;
        float ang = times[b*Tc + t] * expf(-(float)j * LOG1E4_8);
        sh_Hc[t*33 + Ec + q] = (q & 1) ? cosf(ang) : sinf(ang);
    }
    for (int i = tid; i < TAc*32; i += 64){
        sh_Wq[i] = Wq[i];
        int d = i / 32, q = i % 32;
        sh_WkT[q*TAc + d] = Wk[i];
    }
    if (tid < TAc){ sh_bq[tid] = bq[tid]; sh_bk[tid] = bk[tid]; }
    if (tid < Tc) sh_ws[tid] = Ws_[tid];
    __syncthreads();
    for (int i = tid; i < Tc*TAc; i += 64){
        int t = i / TAc, d = i % TAc;
        const float* hc = sh_Hc + t*33;
        float acc = sh_bk[d];
        #pragma unroll
        for (int q = 0; q < 32; q++) acc += hc[q]*sh_WkT[q*TAc + d];
        sh_K[t*11 + d] = acc;
    }
    __syncthreads();
    if (tid < TAc){
        float acc = 0.f;
        #pragma unroll 4
        for (int t = 0; t < Tc; t++) acc += sh_K[t*11 + tid]*sh_ws[t];
        sh_Kw[tid] = acc;
    }
    __syncthreads();
    float bv = 0.f;
    float bsv = bs_[0];
    if (tid < Tc){
        const float* hc = sh_Hc + tid*33;
        float acc = bsv;
        #pragma unroll
        for (int d = 0; d < TAc; d++){
            const float* wq = sh_Wq + d*32;
            float qv = sh_bq[d];
            #pragma unroll
            for (int q = 0; q < 32; q++) qv += hc[q]*wq[q];
            acc += qv*sh_Kw[d];
        }
        bv = acc;
        ws[WS_BETA + idx*Tc + tid] = acc;
    }
    float p0 = (tid < Tc) ? bv : 0.f;
    float p1 = p0*bv;
    #pragma unroll
    for (int off = 32; off; off >>= 1){
        p0 += __shfl_down(p0, off, 64);
        p1 += __shfl_down(p1, off, 64);
    }
    if (tid == 0){
        ws[WS_PART + idx*2]     = p0;
        ws[WS_PART + idx*2 + 1] = p1;
    }
}

// ------- kernel 5: per-(bh,s) LN1-normalize + out1 + out2 + LN2 partials -------
__global__ __launch_bounds__(64) void kF2(const float* __restrict__ lnt_g, const float* __restrict__ lnt_b,
                   const float* __restrict__ Wse, const float* __restrict__ bse,
                   const float* __restrict__ times, float* __restrict__ ws){
    int idx = blockIdx.x;
    int s = idx % Sc; int bh = idx / Sc; int b = bh / Hc_;
    int tid = threadIdx.x;
    __shared__ float sh_Hc[Tc*33];
    __shared__ float sh_beta[Tc];
    __shared__ float sh_o1[32];
    __shared__ float sh_mi[2];
    float p0 = 0.f, p1 = 0.f;
    if (tid < Sc){
        p0 = ws[WS_PART + (bh*Sc + tid)*2];
        p1 = ws[WS_PART + (bh*Sc + tid)*2 + 1];
    }
    #pragma unroll
    for (int off = 32; off; off >>= 1){
        p0 += __shfl_down(p0, off, 64);
        p1 += __shfl_down(p1, off, 64);
    }
    if (tid == 0){
        float m = p0 / (float)(Sc*Tc);
        sh_mi[0] = m;
        sh_mi[1] = rsqrtf(p1 / (float)(Sc*Tc) - m*m + EPSc);
    }
    const float* h2 = ws + WS_H2 + (size_t)bh*Tc*Sc*Ec + s*Ec;
    for (int i4 = tid; i4 < Tc*4; i4 += 64){
        int t = i4 >> 2, c4 = i4 & 3;
        float4 u = *(const float4*)(h2 + t*Sc*Ec + c4*4);
        float* d = sh_Hc + t*33 + c4*4;
        d[0] = u.x; d[1] = u.y; d[2] = u.z; d[3] = u.w;
    }
    for (int i = tid; i < Tc*PEc; i += 64){
        int t = i / PEc, q = i % PEc; int j = q >> 1;
        float ang = times[b*Tc + t] * expf(-(float)j * LOG1E4_8);
        sh_Hc[t*33 + Ec + q] = (q & 1) ? cosf(ang) : sinf(ang);
    }
    __syncthreads();
    float m = sh_mi[0], inv = sh_mi[1];
    if (tid < Tc){
        float bvv = ws[WS_BETA + idx*Tc + tid];
        sh_beta[tid] = (bvv - m)*inv*lnt_g[s*Tc + tid] + lnt_b[s*Tc + tid];
    }
    __syncthreads();
    if (tid < 32){
        float acc = 0.f;
        #pragma unroll 4
        for (int t = 0; t < Tc; t++) acc += sh_beta[t]*sh_Hc[t*33 + tid];
        sh_o1[tid] = lrelu(acc);
    }
    __syncthreads();
    float v = 0.f;
    if (tid < 16){
        float acc = bse[tid];
        const float* w = Wse + tid*32;
        #pragma unroll
        for (int d = 0; d < 32; d++) acc += sh_o1[d]*w[d];
        v = lrelu(acc);
        ws[WS_OUT2 + idx*16 + tid] = v;
    }
    float q0 = v, q1 = v*v;
    #pragma unroll
    for (int off = 32; off; off >>= 1){
        q0 += __shfl_down(q0, off, 64);
        q1 += __shfl_down(q1, off, 64);
    }
    if (tid == 0){
        ws[WS_PART2 + idx*2]     = q0;
        ws[WS_PART2 + idx*2 + 1] = q1;
    }
}

// ------- kernel 6: blocks 0..31: per-(b,h) LN2 + final write; block 32: pair_sim -------
__global__ __launch_bounds__(256) void kF3s(const float* __restrict__ lns_g, const float* __restrict__ lns_b,
                    const float* __restrict__ ws, float* __restrict__ out){
    int tid = threadIdx.x;
    if (blockIdx.x == 32){
        float sq = 0.f, t2 = 0.f;
        for (int i = tid; i < Hc_*Sc*Sc; i += 256){
            float tot = 0.f;
            #pragma unroll
            for (int b = 0; b < Bc; b++){
                float v = ws[WS_ADJ + b*Hc_*Sc*Sc + i];
                sq += v*v; tot += v;
            }
            t2 += tot*tot;
        }
        __shared__ float r0[256], r1[256];
        r0[tid] = sq; r1[tid] = t2; __syncthreads();
        for (int off = 128; off; off >>= 1){
            if (tid < off){ r0[tid] += r0[tid+off]; r1[tid] += r1[tid+off]; }
            __syncthreads();
        }
        if (tid == 0)
            out[Bc*Sc*OUTc] = ((float)Bc*r0[0] - r1[0]) / 49.f / 1296.f;
        return;
    }
    int bh = blockIdx.x; int h = bh % Hc_; int b = bh / Hc_;
    __shared__ float sh_mi[2];
    if (tid < 64){
        float p0 = 0.f, p1 = 0.f;
        if (tid < Sc){
            p0 = ws[WS_PART2 + (bh*Sc + tid)*2];
            p1 = ws[WS_PART2 + (bh*Sc + tid)*2 + 1];
        }
        #pragma unroll
        for (int off = 32; off; off >>= 1){
            p0 += __shfl_down(p0, off, 64);
            p1 += __shfl_down(p1, off, 64);
        }
        if (tid == 0){
            float m = p0 / (float)(Sc*16);
            sh_mi[0] = m;
            sh_mi[1] = rsqrtf(p1 / (float)(Sc*16) - m*m + EPSc);
        }
    }
    __syncthreads();
    float m2 = sh_mi[0], inv2 = sh_mi[1];
    for (int i = tid; i < Sc*16; i += 256){
        int s = i / 16, k = i % 16;
        float v = ws[WS_OUT2 + bh*Sc*16 + i];
        out[(b*Sc + s)*OUTc + h*16 + k] = (v - m2)*inv2*lns_g[i] + lns_b[i];
    }
}

extern "C" void kernel_launch(void* const* d_in, const int* in_sizes, int n_in,
                              void* d_out, int out_size, void* d_ws, size_t ws_size,
                              hipStream_t stream){
    const float* x     = (const float*)d_in[0];
    const float* times = (const float*)d_in[1];
    const float* mask  = (const float*)d_in[2];
    const float* bn_g  = (const float*)d_in[3];
    const float* bn_b  = (const float*)d_in[4];
    const float* obs   = (const float*)d_in[5];
    const float* attn  = (const float*)d_in[6];
    const float* bidw  = (const float*)d_in[7];
    const float* projW = (const float*)d_in[8];
    const float* projb = (const float*)d_in[9];
    const float* Wq    = (const float*)d_in[10];
    const float* bq    = (const float*)d_in[11];
    const float* Wk    = (const float*)d_in[12];
    const float* bk    = (const float*)d_in[13];
    const float* Ws_   = (const float*)d_in[14];
    const float* bs_   = (const float*)d_in[15];
    const float* lnt_g = (const float*)d_in[16];
    const float* lnt_b = (const float*)d_in[17];
    const float* Wse   = (const float*)d_in[18];
    const float* bse   = (const float*)d_in[19];
    const float* lns_g = (const float*)d_in[20];
    const float* lns_b = (const float*)d_in[21];
    float* ws  = (float*)d_ws;
    float* out = (float*)d_out;

    k_layer01<<<Bc*Hc_*Tc, 256, 0, stream>>>(x, times, mask, bn_g, bn_b, obs, attn, bidw, projW, projb, ws);
    k_adjpart<<<Bc*Hc_*6, 256, 0, stream>>>(mask, ws);
    k_prune<<<Bc*Hc_*24, 256, 0, stream>>>(ws);
    k_layer1mp<<<Bc*Hc_*Tc, 256, 0, stream>>>(bidw, ws);
    kF1<<<Bc*Hc_*Sc, 64, 0, stream>>>(Wq, bq, Wk, bk, Ws_, bs_, times, ws);
    kF2<<<Bc*Hc_*Sc, 64, 0, stream>>>(lnt_g, lnt_b, Wse, bse, times, ws);
    kF3s<<<Bc*Hc_ + 1, 256, 0, stream>>>(lns_g, lns_b, ws, out);
}